// Round 15
// baseline (177.757 us; speedup 1.0000x reference)
//
#include <hip/hip_runtime.h>

#define T_LEN 512
#define B_SZ  256
#define N_ST  128

#if defined(__has_builtin)
# if __has_builtin(__builtin_amdgcn_fdot2_f32_bf16)
#  define HAVE_DOT2 1
# endif
#endif
#ifndef HAVE_DOT2
# define HAVE_DOT2 0
#endif

typedef unsigned int uint32;
typedef __bf16 bf16x2 __attribute__((ext_vector_type(2)));
typedef float f2v __attribute__((ext_vector_type(2)));

__device__ __forceinline__ uint32 bf16rn(float f) {   // RNE bf16 (no NaNs here)
    uint32 u = __builtin_bit_cast(uint32, f);
    u += 0x7fffu + ((u >> 16) & 1u);
    return u >> 16;
}
__device__ __forceinline__ uint32 pack2(float lo, float hi) {
    return bf16rn(lo) | (bf16rn(hi) << 16);
}
__device__ __forceinline__ uint32 cvtpk(float lo, float hi) {   // HW packed cvt, RNE
    uint32 r;
    asm("v_cvt_pk_bf16_f32 %0, %1, %2" : "=v"(r) : "v"(lo), "v"(hi));
    return r;
}
__device__ __forceinline__ float readlane0(float v) {
    return __builtin_bit_cast(float, (uint32)__builtin_amdgcn_readlane(__builtin_bit_cast(int, v), 0));
}
__device__ __forceinline__ uint32 rdlane(uint32 v, int i) {   // lane i -> uniform (SGPR)
    return (uint32)__builtin_amdgcn_readlane((int)v, i);
}
__device__ __forceinline__ float dot2b(uint32 a, uint32 b, float c) {
#if HAVE_DOT2
    return __builtin_amdgcn_fdot2_f32_bf16(__builtin_bit_cast(bf16x2, a),
                                           __builtin_bit_cast(bf16x2, b), c, false);
#else
    float alo = __builtin_bit_cast(float, a << 16);
    float ahi = __builtin_bit_cast(float, a & 0xffff0000u);
    float blo = __builtin_bit_cast(float, b << 16);
    float bhi = __builtin_bit_cast(float, b & 0xffff0000u);
    return fmaf(ahi, bhi, fmaf(alo, blo, c));
#endif
}

// ws layout (floats): [0..255] logZ_b ; [256..511] score_b ; [512..767] lens (int)

__global__ __launch_bounds__(64) void lengths_kernel(const unsigned char* __restrict__ mask_raw,
                                                     int* __restrict__ lens) {
    int b = blockIdx.x;   // 256 blocks
    int l = threadIdx.x;  // 64 threads
    // Detect mask encoding (mask[0][*] always true since lengths >= T/2):
    // u8: byte[1]=1 ; i32: bytes1,2=0 ; f32: 1.0f -> byte[2]=0x80
    unsigned char b1 = mask_raw[1], b2 = mask_raw[2];
    int mode = (b1 != 0) ? 0 : ((b2 != 0) ? 2 : 1);
    int cnt = 0;
    if (mode == 0) {
        #pragma unroll
        for (int k = 0; k < 8; ++k) cnt += (mask_raw[(l * 8 + k) * B_SZ + b] != 0);
    } else if (mode == 1) {
        const int* m = (const int*)mask_raw;
        #pragma unroll
        for (int k = 0; k < 8; ++k) cnt += (m[(l * 8 + k) * B_SZ + b] != 0);
    } else {
        const float* m = (const float*)mask_raw;
        #pragma unroll
        for (int k = 0; k < 8; ++k) cnt += (m[(l * 8 + k) * B_SZ + b] != 0.0f);
    }
    #pragma unroll
    for (int off = 1; off < 64; off <<= 1) cnt += __shfl_xor(cnt, off);
    if (l == 0) lens[b] = cnt;
}

// Meet-in-the-middle CRF forward: logZ = log <a_m, y_m>.
//   wave 0: a_t = ee_t o (E^T a_{t-1}),  t = 1..m        (E columns)
//   wave 1: y_{t-1} = E (ee_t o y_t),    t = len-1..m+1  (E rows)
// m = min(256, len-1). vs R14: the state all-gather uses v_readlane broadcast
// (VALU, const lane indices) feeding dot2's scalar operand -- ZERO DS ops in
// the recurrence. R14 counters: ~890 cyc/step stall with DS write->16x b128
// read on the carried path; this removes that component entirely.
__global__ void __attribute__((amdgpu_flat_work_group_size(128, 128), amdgpu_waves_per_eu(1, 1)))
forward_kernel(
        const float* __restrict__ emit,
        const float* __restrict__ trans,
        const float* __restrict__ strans,
        const float* __restrict__ etrans,
        const int* __restrict__ lens,
        float* __restrict__ logZ_out) {
    const int b   = blockIdx.x;
    const int tid = threadIdx.x;      // 0..127
    const int wid = tid >> 6;         // 0 = forward, 1 = backward
    const int l   = tid & 63;
    const int c0  = 2 * l, c1 = 2 * l + 1;   // owned cols (fwd) / rows (bwd)

    __shared__ float meetA[N_ST], meetY[N_ST];
    __shared__ float maccSh[2], red2[2];

    const int len = lens[b];
    const int m = (len - 1 < 256) ? (len - 1) : 256;
    const float* eb = emit + (size_t)b * N_ST;
    const size_t TS2 = (size_t)B_SZ * N_ST / 2;            // float2 stride per t
    const f2v* ebv = (const f2v*)eb;                        // lane reads ebv[t*TS2 + l]

    // Broadcast-matvec inner loop: group q = lanes 4q..4q+3 words via readlane
    #define GROUP(Q, AW, EA_, EB_) { \
        const uint32 w0 = rdlane(AW, 4 * (Q) + 0); \
        const uint32 w1 = rdlane(AW, 4 * (Q) + 1); \
        const uint32 w2 = rdlane(AW, 4 * (Q) + 2); \
        const uint32 w3 = rdlane(AW, 4 * (Q) + 3); \
        A0 = dot2b(w0, EA_[4 * (Q) + 0], A0);  B0 = dot2b(w0, EB_[4 * (Q) + 0], B0); \
        A1 = dot2b(w1, EA_[4 * (Q) + 1], A1);  B1 = dot2b(w1, EB_[4 * (Q) + 1], B1); \
        A2 = dot2b(w2, EA_[4 * (Q) + 2], A2);  B2 = dot2b(w2, EB_[4 * (Q) + 2], B2); \
        A3 = dot2b(w3, EA_[4 * (Q) + 3], A3);  B3 = dot2b(w3, EB_[4 * (Q) + 3], B3); }
    #define MATVEC(AW, EA_, EB_) \
        GROUP(0, AW, EA_, EB_)  GROUP(1, AW, EA_, EB_)  GROUP(2, AW, EA_, EB_)  GROUP(3, AW, EA_, EB_) \
        GROUP(4, AW, EA_, EB_)  GROUP(5, AW, EA_, EB_)  GROUP(6, AW, EA_, EB_)  GROUP(7, AW, EA_, EB_) \
        GROUP(8, AW, EA_, EB_)  GROUP(9, AW, EA_, EB_)  GROUP(10, AW, EA_, EB_) GROUP(11, AW, EA_, EB_) \
        GROUP(12, AW, EA_, EB_) GROUP(13, AW, EA_, EB_) GROUP(14, AW, EA_, EB_) GROUP(15, AW, EA_, EB_)

    if (wid == 0) {
        // ---- forward: E columns c0, c1 packed over i-pairs ----
        uint32 EA[64], EB[64];
        #pragma unroll
        for (int p = 0; p < 64; ++p) {
            EA[p] = pack2(__expf(trans[(2 * p) * N_ST + c0]), __expf(trans[(2 * p + 1) * N_ST + c0]));
            EB[p] = pack2(__expf(trans[(2 * p) * N_ST + c1]), __expf(trans[(2 * p + 1) * N_ST + c1]));
        }
        float aA = __expf(strans[c0] + eb[c0]);
        float aB = __expf(strans[c1] + eb[c1]);
        uint32 aw = pack2(aA, aB);                         // the whole state: 1 VGPR
        float Macc = 0.f, inv = 1.0f;
        #define EIDX(T) ((size_t)(((T) <= m) ? (T) : m) * TS2 + l)
        f2v p0 = ebv[EIDX(1)];
        f2v p1 = ebv[EIDX(2)];
        f2v p2 = ebv[EIDX(3)];
        f2v p3 = ebv[EIDX(4)];
        for (int t = 1; t <= m; ++t) {
            const f2v pn = ebv[EIDX(t + 4)];               // prefetch, 4 iters ahead
            const float ee0 = __expf(p0.x), ee1 = __expf(p0.y);
            float A0 = 0, A1 = 0, A2 = 0, A3 = 0, B0 = 0, B1 = 0, B2 = 0, B3 = 0;
            MATVEC(aw, EA, EB)                             // readlane broadcast, no DS
            const float rA = (A0 + A1) + (A2 + A3);
            const float rB = (B0 + B1) + (B2 + B3);
            Macc -= __logf(inv);                           // bookkeeping (off write path)
            aA = ee0 * rA * inv;                           // delayed uniform normalizer
            aB = ee1 * rB * inv;
            aw = cvtpk(aA, aB);
            inv = __builtin_amdgcn_rcpf(readlane0(rA));
            p0 = p1; p1 = p2; p2 = p3; p3 = pn;
        }
        #undef EIDX
        meetA[c0] = aA; meetA[c1] = aB;
        if (l == 0) maccSh[0] = Macc;
    } else {
        // ---- backward: E rows c0, c1 packed over j-pairs (contiguous trans reads) ----
        uint32 RA[64], RB[64];
        #pragma unroll
        for (int p = 0; p < 64; ++p) {
            RA[p] = pack2(__expf(trans[c0 * N_ST + 2 * p]), __expf(trans[c0 * N_ST + 2 * p + 1]));
            RB[p] = pack2(__expf(trans[c1 * N_ST + 2 * p]), __expf(trans[c1 * N_ST + 2 * p + 1]));
        }
        float y0 = __expf(etrans[c0]);                     // y_{len-1} = exp(etrans)
        float y1 = __expf(etrans[c1]);
        float Maccb = 0.f, invb = 1.0f;
        const int t0 = len - 1;
        #define EIDXB(T) ((size_t)(((T) > m) ? (T) : (m + 1)) * TS2 + l)
        f2v p0 = ebv[EIDXB(t0)];
        f2v p1 = ebv[EIDXB(t0 - 1)];
        f2v p2 = ebv[EIDXB(t0 - 2)];
        f2v p3 = ebv[EIDXB(t0 - 3)];
        for (int t = t0; t > m; --t) {
            const f2v pn = ebv[EIDXB(t - 4)];              // prefetch, 4 iters ahead
            const float ee0 = __expf(p0.x), ee1 = __expf(p0.y);
            const uint32 zw = cvtpk(ee0 * y0, ee1 * y1);   // z = ee_t o y_t : 1 VGPR
            float A0 = 0, A1 = 0, A2 = 0, A3 = 0, B0 = 0, B1 = 0, B2 = 0, B3 = 0;
            MATVEC(zw, RA, RB)                             // readlane broadcast, no DS
            const float rR = (A0 + A1) + (A2 + A3);
            const float rS = (B0 + B1) + (B2 + B3);
            Maccb -= __logf(invb);
            y0 = rR * invb;                                // delayed normalizer, mirrored
            y1 = rS * invb;
            invb = __builtin_amdgcn_rcpf(readlane0(rR));
            p0 = p1; p1 = p2; p2 = p3; p3 = pn;
        }
        #undef EIDXB
        meetY[c0] = y0; meetY[c1] = y1;
        if (l == 0) maccSh[1] = Maccb;
    }
    #undef MATVEC
    #undef GROUP

    // ---- meet: logZ = MaccF + MaccB + log( sum_j a_m[j] * y_m[j] ) ----
    __syncthreads();
    float v = meetA[tid] * meetY[tid];
    #pragma unroll
    for (int off = 1; off < 64; off <<= 1) v += __shfl_xor(v, off);
    if (l == 0) red2[wid] = v;
    __syncthreads();
    if (tid == 0) logZ_out[b] = maccSh[0] + maccSh[1] + __logf(red2[0] + red2[1]);
}

__global__ __launch_bounds__(128) void score_kernel(
        const float* __restrict__ emit,
        const int* __restrict__ target,
        const float* __restrict__ trans,
        const float* __restrict__ strans,
        const float* __restrict__ etrans,
        const int* __restrict__ lens,
        float* __restrict__ score_out) {
    const int b   = blockIdx.x;
    const int tid = threadIdx.x;  // 128
    const int len = lens[b];
    float local = 0.f;
    for (int t = tid; t < len; t += 128) {
        int tgt = target[t * B_SZ + b];
        float v = emit[(size_t)t * (B_SZ * N_ST) + b * N_ST + tgt];
        if (t > 0) v += trans[target[(t - 1) * B_SZ + b] * N_ST + tgt];
        local += v;
    }
    if (tid == 0) {
        local += strans[target[b]];
        local += etrans[target[(len - 1) * B_SZ + b]];
    }
    #pragma unroll
    for (int off = 1; off < 64; off <<= 1) local += __shfl_xor(local, off);
    __shared__ float partial[2];
    if ((tid & 63) == 0) partial[tid >> 6] = local;
    __syncthreads();
    if (tid == 0) score_out[b] = partial[0] + partial[1];
}

__global__ __launch_bounds__(256) void finalize_kernel(
        const float* __restrict__ logZ,
        const float* __restrict__ score,
        float* __restrict__ out) {
    int tid = threadIdx.x;  // 256
    float v = logZ[tid] - score[tid];
    #pragma unroll
    for (int off = 1; off < 64; off <<= 1) v += __shfl_xor(v, off);
    __shared__ float p[4];
    if ((tid & 63) == 0) p[tid >> 6] = v;
    __syncthreads();
    if (tid == 0) out[0] = (p[0] + p[1] + p[2] + p[3]) / 256.0f;
}

extern "C" void kernel_launch(void* const* d_in, const int* in_sizes, int n_in,
                              void* d_out, int out_size, void* d_ws, size_t ws_size,
                              hipStream_t stream) {
    const float*         emit   = (const float*)d_in[0];
    const int*           target = (const int*)d_in[1];
    const unsigned char* mask   = (const unsigned char*)d_in[2];
    const float*         trans  = (const float*)d_in[3];
    const float*         strans = (const float*)d_in[4];
    const float*         etrans = (const float*)d_in[5];

    float* ws     = (float*)d_ws;
    float* logZb  = ws;            // 256
    float* scoreb = ws + 256;      // 256
    int*   lens   = (int*)(ws + 512);

    lengths_kernel<<<B_SZ, 64, 0, stream>>>(mask, lens);
    forward_kernel<<<B_SZ, 128, 0, stream>>>(emit, trans, strans, etrans, lens, logZb);
    score_kernel<<<B_SZ, 128, 0, stream>>>(emit, target, trans, strans, etrans, lens, scoreb);
    finalize_kernel<<<1, 256, 0, stream>>>(logZb, scoreb, (float*)d_out);
}